// Round 4
// baseline (783.044 us; speedup 1.0000x reference)
//
#include <hip/hip_runtime.h>

#define T_LEN 512
#define OSTRIDE ((size_t)2048 * 512 * 32)  // elements per output copy

__device__ __forceinline__ float rlf(float v, int l) {
  return __int_as_float(__builtin_amdgcn_readlane(__float_as_int(v), l));
}
// quad_perm broadcast of quad-lane sel (0..3): ctrl = sel * 0x55
#define QB(v, pat) __int_as_float(__builtin_amdgcn_mov_dpp(__float_as_int(v), (pat), 0xF, 0xF, false))

// ---------------------------------------------------------------------------
// Kernel 1: pre-net.  One thread per (b,t) row: 32 -> 16 -> 16 -> 16.
// Weights are wave-uniform -> s_load into SGPRs (no LDS, no VALU for loads);
// all FMAs are v_fmac(sgpr, vgpr).
// ---------------------------------------------------------------------------
__global__ __launch_bounds__(256) void prenet_kernel(
    const float* __restrict__ seq,
    const float* __restrict__ w1, const float* __restrict__ b1,
    const float* __restrict__ w2, const float* __restrict__ b2,
    const float* __restrict__ w3, const float* __restrict__ b3,
    float* __restrict__ xws) {
  const int tid = threadIdx.x;
  const size_t r = (size_t)blockIdx.x * 256 + tid;  // row id, < 1,048,576
  const float* sp = seq + r * 32;

  float in[32];
#pragma unroll
  for (int q = 0; q < 8; ++q) {
    float4 v = ((const float4*)sp)[q];
    in[q * 4 + 0] = v.x;
    in[q * 4 + 1] = v.y;
    in[q * 4 + 2] = v.z;
    in[q * 4 + 3] = v.w;
  }

  float y1[16];
#pragma unroll
  for (int j = 0; j < 16; ++j) {
    float a0 = b1[j], a1 = 0.f, a2 = 0.f, a3 = 0.f;
#pragma unroll
    for (int k = 0; k < 32; k += 4) {
      a0 = __builtin_fmaf(w1[j * 32 + k + 0], in[k + 0], a0);
      a1 = __builtin_fmaf(w1[j * 32 + k + 1], in[k + 1], a1);
      a2 = __builtin_fmaf(w1[j * 32 + k + 2], in[k + 2], a2);
      a3 = __builtin_fmaf(w1[j * 32 + k + 3], in[k + 3], a3);
    }
    float s = (a0 + a1) + (a2 + a3);
    y1[j] = s >= 0.f ? s : 0.01f * s;
  }

  float y2[16];
#pragma unroll
  for (int j = 0; j < 16; ++j) {
    float a0 = b2[j], a1 = 0.f, a2 = 0.f, a3 = 0.f;
#pragma unroll
    for (int k = 0; k < 16; k += 4) {
      a0 = __builtin_fmaf(w2[j * 16 + k + 0], y1[k + 0], a0);
      a1 = __builtin_fmaf(w2[j * 16 + k + 1], y1[k + 1], a1);
      a2 = __builtin_fmaf(w2[j * 16 + k + 2], y1[k + 2], a2);
      a3 = __builtin_fmaf(w2[j * 16 + k + 3], y1[k + 3], a3);
    }
    float s = (a0 + a1) + (a2 + a3);
    y2[j] = s >= 0.f ? s : 0.01f * s;
  }

  float y3[16];
#pragma unroll
  for (int j = 0; j < 16; ++j) {
    float a0 = b3[j], a1 = 0.f, a2 = 0.f, a3 = 0.f;
#pragma unroll
    for (int k = 0; k < 16; k += 4) {
      a0 = __builtin_fmaf(w3[j * 16 + k + 0], y2[k + 0], a0);
      a1 = __builtin_fmaf(w3[j * 16 + k + 1], y2[k + 1], a1);
      a2 = __builtin_fmaf(w3[j * 16 + k + 2], y2[k + 2], a2);
      a3 = __builtin_fmaf(w3[j * 16 + k + 3], y2[k + 3], a3);
    }
    y3[j] = (a0 + a1) + (a2 + a3);
  }

  float* op = xws + r * 16;
#pragma unroll
  for (int q = 0; q < 4; ++q)
    ((float4*)op)[q] =
        make_float4(y3[q * 4 + 0], y3[q * 4 + 1], y3[q * 4 + 2], y3[q * 4 + 3]);
}

// ---------------------------------------------------------------------------
// Kernel 2: recurrent encoder+decoder.  One wave per batch sample.
// Lane j owns gate gi=(j&3)*16+(j>>2); gate weights PRESCALED by
// sK = isTanh ? 2 : -1 so activation needs no select.  h (and decoder t1)
// broadcast via readlane into SGPR floats used DIRECTLY as fmac src0 — no
// vector repack.  x rows via scalar loads.  Decoder uses the composed matrix
// M = sK*Wih@W2 so the w2 GEMV and start-vector broadcast disappear.
// ---------------------------------------------------------------------------
#define CELL(WX, XA, BB)                                                    \
  do {                                                                      \
    float a0 = (BB), a1 = 0.f, a2 = 0.f, a3 = 0.f;                          \
    _Pragma("unroll") for (int k = 0; k < 16; k += 4) {                     \
      a0 = __builtin_fmaf(WX[k + 0], XA[k + 0], a0);                        \
      a1 = __builtin_fmaf(WX[k + 1], XA[k + 1], a1);                        \
      a2 = __builtin_fmaf(WX[k + 2], XA[k + 2], a2);                        \
      a3 = __builtin_fmaf(WX[k + 3], XA[k + 3], a3);                        \
    }                                                                       \
    _Pragma("unroll") for (int k = 0; k < 16; k += 4) {                     \
      a0 = __builtin_fmaf(whhr[k + 0], hk[k + 0], a0);                      \
      a1 = __builtin_fmaf(whhr[k + 1], hk[k + 1], a1);                      \
      a2 = __builtin_fmaf(whhr[k + 2], hk[k + 2], a2);                      \
      a3 = __builtin_fmaf(whhr[k + 3], hk[k + 3], a3);                      \
    }                                                                       \
    float g = (a0 + a1) + (a2 + a3);                                        \
    float ee = __expf(g);                                                   \
    float rr = __builtin_amdgcn_rcpf(1.0f + ee);                            \
    float act = __builtin_fmaf(sa, rr, sb);                                 \
    float ii = QB(act, 0x00);                                               \
    float ff = QB(act, 0x55);                                               \
    float gg = QB(act, 0xAA);                                               \
    float oo = QB(act, 0xFF);                                               \
    c = __builtin_fmaf(ff, c, ii * gg);                                     \
    float th = __builtin_fmaf(                                              \
        -2.0f, __builtin_amdgcn_rcpf(1.0f + __expf(c + c)), 1.0f);          \
    h = oo * th;                                                            \
    _Pragma("unroll") for (int k = 0; k < 16; ++k) hk[k] = rlf(h, 4 * k);   \
  } while (0)

__global__ __launch_bounds__(256) void lstm_rec_kernel(
    const float* __restrict__ Wih, const float* __restrict__ Whh,
    const float* __restrict__ bih, const float* __restrict__ bhh,
    const float* __restrict__ hw1, const float* __restrict__ hb1,
    const float* __restrict__ hw2, const float* __restrict__ hb2,
    const float* __restrict__ pw, const float* __restrict__ pb,
    const float* __restrict__ xws, float* __restrict__ out) {
  const int lane = threadIdx.x & 63;
  const int bu =
      __builtin_amdgcn_readfirstlane(blockIdx.x * 4 + (threadIdx.x >> 6));
  const int hr = lane >> 2;             // h index 0..15 (quad id)
  const int gi = (lane & 3) * 16 + hr;  // gate row 0..63
  const bool isT = (lane & 3) == 2;     // quad-lane 2 = g gate (tanh)

  const float sK = isT ? 2.0f : -1.0f;  // gate prescale
  const float sa = isT ? -2.0f : 1.0f;  // act = sa*rr + sb
  const float sb = isT ? 1.0f : 0.0f;

  float wihr[16], whhr[16];
#pragma unroll
  for (int k = 0; k < 16; ++k) {
    wihr[k] = Wih[gi * 16 + k] * sK;
    whhr[k] = Whh[gi * 16 + k] * sK;
  }
  const float bias = (bih[gi] + bhh[gi]) * sK;

  float h = 0.f, c = 0.f;
  float hk[16];  // wave-uniform copy of h (SGPRs)
#pragma unroll
  for (int k = 0; k < 16; ++k) hk[k] = 0.f;

  const float* xb = xws + (size_t)bu * (T_LEN * 16);  // uniform pointer

  // ---------------- encoder: 512 steps, x via scalar loads ----------------
  float xA[16], xB[16];
#pragma unroll
  for (int k = 0; k < 16; ++k) xA[k] = xb[k];
  for (int t = 0; t < T_LEN; t += 2) {
    const float* n1 = xb + (size_t)(t + 1) * 16;
#pragma unroll
    for (int k = 0; k < 16; ++k) xB[k] = n1[k];
    CELL(wihr, xA, bias);
    const int t2 = (t + 2 < T_LEN) ? (t + 2) : (T_LEN - 1);
    const float* n2 = xb + (size_t)t2 * 16;
#pragma unroll
    for (int k = 0; k < 16; ++k) xA[k] = n2[k];
    CELL(wihr, xB, bias);
  }

  // ---------------- decoder setup ----------------
  // Fused GEMV rows: lanes 0..31 -> post_w row=lane; 32..63 -> h2l_w1 row=lane&15.
  const int mrow = (lane < 32) ? lane : (lane & 15);
  const float* msrc = (lane < 32) ? (pw + mrow * 16) : (hw1 + mrow * 16);
  const float mbias = (lane < 32) ? pb[mrow] : hb1[mrow];
  const float sl = (lane < 32) ? 1.0f : 0.01f;  // leaky only on w1 lanes
  float mr[16];
#pragma unroll
  for (int k = 0; k < 16; ++k) mr[k] = msrc[k];

  // Composed matrix: Mr[k] = sum_j (sK*Wih[gi,j]) * w2[j,k]  (prescaled)
  // and mbias2 = bias + sum_j (sK*Wih[gi,j]) * b2[j].
  float Mr[16];
#pragma unroll
  for (int k = 0; k < 16; ++k) Mr[k] = 0.f;
#pragma unroll
  for (int j = 0; j < 16; ++j) {
#pragma unroll
    for (int k = 0; k < 16; ++k)
      Mr[k] = __builtin_fmaf(wihr[j], hw2[j * 16 + k], Mr[k]);
  }
  float mbias2 = bias;
#pragma unroll
  for (int j = 0; j < 16; ++j)
    mbias2 = __builtin_fmaf(wihr[j], hb2[j], mbias2);

  // start0 = pre-net output at t = T-1 (uniform loads)
  float xk[16];
  {
    const float* src = xb + (size_t)(T_LEN - 1) * 16;
#pragma unroll
    for (int k = 0; k < 16; ++k) xk[k] = src[k];
  }

  float uk[16];
  const size_t obase = (size_t)bu * (T_LEN * 32) + (lane & 31);

  // ---------------- decoder: 512 steps ----------------
  CELL(wihr, xk, bias);  // first cell consumes the real start0

  for (int t = 0; t < T_LEN; ++t) {
    // fused GEMV on current h: lanes 0-31 -> out rows, 32-47 -> t1 rows
    float p0 = mbias, p1 = 0.f, p2 = 0.f, p3 = 0.f;
#pragma unroll
    for (int k = 0; k < 16; k += 4) {
      p0 = __builtin_fmaf(mr[k + 0], hk[k + 0], p0);
      p1 = __builtin_fmaf(mr[k + 1], hk[k + 1], p1);
      p2 = __builtin_fmaf(mr[k + 2], hk[k + 2], p2);
      p3 = __builtin_fmaf(mr[k + 3], hk[k + 3], p3);
    }
    float y0 = (p0 + p1) + (p2 + p3);
    float yv = fmaxf(y0, y0 * sl);  // leaky where sl=0.01, identity where sl=1

    if (lane < 32) {  // outputs time-reversed; both copies
      const size_t off = obase + (size_t)(T_LEN - 1 - t) * 32;
      out[off] = yv;
      out[off + OSTRIDE] = yv;
    }

    if (t + 1 < T_LEN) {
      // t1 broadcast from lanes 32..47, then composed cell:
      // g = Mr . t1 + Whh . h + mbias2
#pragma unroll
      for (int k = 0; k < 16; ++k) uk[k] = rlf(yv, 32 + k);
      CELL(Mr, uk, mbias2);
    }
  }
}

extern "C" void kernel_launch(void* const* d_in, const int* in_sizes, int n_in,
                              void* d_out, int out_size, void* d_ws, size_t ws_size,
                              hipStream_t stream) {
  const float* seq = (const float*)d_in[0];
  const float* pre_w1 = (const float*)d_in[1];
  const float* pre_b1 = (const float*)d_in[2];
  const float* pre_w2 = (const float*)d_in[3];
  const float* pre_b2 = (const float*)d_in[4];
  const float* pre_w3 = (const float*)d_in[5];
  const float* pre_b3 = (const float*)d_in[6];
  const float* enc_Wih = (const float*)d_in[7];
  const float* enc_Whh = (const float*)d_in[8];
  const float* enc_bih = (const float*)d_in[9];
  const float* enc_bhh = (const float*)d_in[10];
  const float* h2l_w1 = (const float*)d_in[11];
  const float* h2l_b1 = (const float*)d_in[12];
  const float* h2l_w2 = (const float*)d_in[13];
  const float* h2l_b2 = (const float*)d_in[14];
  const float* post_w = (const float*)d_in[15];
  const float* post_b = (const float*)d_in[16];

  float* xws = (float*)d_ws;  // (B*T, 16) fp32 = 64 MiB

  prenet_kernel<<<dim3(4096), dim3(256), 0, stream>>>(
      seq, pre_w1, pre_b1, pre_w2, pre_b2, pre_w3, pre_b3, xws);

  lstm_rec_kernel<<<dim3(512), dim3(256), 0, stream>>>(
      enc_Wih, enc_Whh, enc_bih, enc_bhh, h2l_w1, h2l_b1, h2l_w2, h2l_b2,
      post_w, post_b, xws, (float*)d_out);
}